// Round 24
// baseline (156.858 us; speedup 1.0000x reference)
//
#include <hip/hip_runtime.h>
#include <hip/hip_bf16.h>

#define SEQ 4096
#define NB 64
#define H2 256
#define MROWS (SEQ * NB)   // 262144

typedef short bf16x8 __attribute__((ext_vector_type(8)));
typedef int   i32x4  __attribute__((ext_vector_type(4)));
typedef float f32x4  __attribute__((ext_vector_type(4)));

__device__ __forceinline__ float fast_tanh(float x) {
    float e = __expf(2.0f * x);
    return 1.0f - 2.0f * __builtin_amdgcn_rcpf(e + 1.0f);
}

// -------- pack W (fp32 [256][256] d-major) -> bf16 MFMA B-fragment order ----
// Wp[((kk*16+n)*64 + l)*8 + i] = bf16(W[(kk*32 + 8*(l>>4) + i)*256 + n*16 + (l&15)])
__global__ __launch_bounds__(256)
void pack_w_kernel(const float* __restrict__ W, __hip_bfloat16* __restrict__ Wp) {
    int t = blockIdx.x * 256 + threadIdx.x;   // 0..8191
    int l  = t & 63;
    int n  = (t >> 6) & 15;
    int kk = t >> 10;
    int e  = n * 16 + (l & 15);
    int d0 = kk * 32 + 8 * (l >> 4);
    union { __hip_bfloat16 h[8]; i32x4 v; } cv;
#pragma unroll
    for (int i = 0; i < 8; ++i) cv.h[i] = __float2bfloat16(W[(d0 + i) * H2 + e]);
    *reinterpret_cast<i32x4*>(&Wp[(size_t)t * 8]) = cv.v;
}

// -------- fused MFMA GEMM + tanh + proj-dot -> fp32 logits attnS[s*64+b] ----
// R17/R23 champion structure; ONE change: W staging via global_load_lds(16B)
// async DMA (issued before the MFMA loop, drained by the end-of-kk barrier).
__global__ __launch_bounds__(256, 2)
void mfma_logits_kernel(const float* __restrict__ enc,
                        const __hip_bfloat16* __restrict__ Wp,
                        const float* __restrict__ bias,
                        const float* __restrict__ proj,
                        float* __restrict__ attnS) {
    __shared__ __hip_bfloat16 aT[2][128][40];   // 128 rows x 32 d (pad->40)
    __shared__ __hip_bfloat16 wT[2][8192];      // 16 KiB W-chunk per K-step

    const int tid  = threadIdx.x;
    const int lane = tid & 63;
    const int w    = tid >> 6;
    const long r0  = (long)blockIdx.x * 128;

    f32x4 acc[2][16];
#pragma unroll
    for (int rt = 0; rt < 2; ++rt)
#pragma unroll
        for (int n = 0; n < 16; ++n) acc[rt][n] = (f32x4)(0.0f);

    // ---- prologue: stage K-chunk 0 (A: reg+cvt; W: async DMA) ----
#pragma unroll
    for (int j = 0; j < 4; ++j) {
        // lane's 16B from Wp -> wT[0][wave-uniform base + lane*8]
        __builtin_amdgcn_global_load_lds(
            (const void*)(Wp + (size_t)j * 2048 + (size_t)tid * 8),
            (void*)&wT[0][j * 2048 + w * 512], 16, 0, 0);
    }
#pragma unroll
    for (int it = 0; it < 4; ++it) {
        int q = it * 256 + tid;
        int row = q >> 3;
        int dc = (q & 7) * 4;
        float4 v = *reinterpret_cast<const float4*>(&enc[(r0 + row) * H2 + dc]);
        union { __hip_bfloat16 h[4]; uint2 u; } cv;
        cv.h[0] = __float2bfloat16(v.x); cv.h[1] = __float2bfloat16(v.y);
        cv.h[2] = __float2bfloat16(v.z); cv.h[3] = __float2bfloat16(v.w);
        *reinterpret_cast<uint2*>(&aT[0][row][dc]) = cv.u;
    }
    __syncthreads();

    int buf = 0;
#pragma unroll
    for (int kk = 0; kk < 8; ++kk) {
        // W prefetch: async DMA straight into the other LDS buffer
        if (kk < 7) {
#pragma unroll
            for (int j = 0; j < 4; ++j) {
                __builtin_amdgcn_global_load_lds(
                    (const void*)(Wp + (size_t)(kk + 1) * 8192 + (size_t)j * 2048
                                  + (size_t)tid * 8),
                    (void*)&wT[buf ^ 1][j * 2048 + w * 512], 16, 0, 0);
            }
        }
        // A prefetch into registers (needs fp32->bf16 cvt)
        float4 av[4];
        if (kk < 7) {
#pragma unroll
            for (int it = 0; it < 4; ++it) {
                int q = it * 256 + tid;
                int row = q >> 3;
                int dc = (q & 7) * 4;
                av[it] = *reinterpret_cast<const float4*>(
                    &enc[(r0 + row) * H2 + (kk + 1) * 32 + dc]);
            }
        }
        // compute on current buffer
        bf16x8 af[2];
#pragma unroll
        for (int rt = 0; rt < 2; ++rt)
            af[rt] = *reinterpret_cast<const bf16x8*>(
                &aT[buf][w * 32 + rt * 16 + (lane & 15)][8 * (lane >> 4)]);
#pragma unroll
        for (int n = 0; n < 16; ++n) {
            bf16x8 bv = *reinterpret_cast<const bf16x8*>(&wT[buf][(n * 64 + lane) * 8]);
            acc[0][n] = __builtin_amdgcn_mfma_f32_16x16x32_bf16(af[0], bv, acc[0][n], 0, 0, 0);
            acc[1][n] = __builtin_amdgcn_mfma_f32_16x16x32_bf16(af[1], bv, acc[1][n], 0, 0, 0);
        }
        // write prefetched A into the other buffer
        if (kk < 7) {
#pragma unroll
            for (int it = 0; it < 4; ++it) {
                int q = it * 256 + tid;
                int row = q >> 3;
                int dc = (q & 7) * 4;
                union { __hip_bfloat16 h[4]; uint2 u; } cv;
                cv.h[0] = __float2bfloat16(av[it].x); cv.h[1] = __float2bfloat16(av[it].y);
                cv.h[2] = __float2bfloat16(av[it].z); cv.h[3] = __float2bfloat16(av[it].w);
                *reinterpret_cast<uint2*>(&aT[buf ^ 1][row][dc]) = cv.u;
            }
        }
        __syncthreads();   // drains vmcnt (DMA) + lgkmcnt before buffer swap
        buf ^= 1;
    }

    // ---- epilogue: tanh + proj-dot + 16-lane reduce; fp32 store ----
    float biasv[16], projv[16];
#pragma unroll
    for (int n = 0; n < 16; ++n) {
        int e = n * 16 + (lane & 15);
        biasv[n] = bias[e];
        projv[n] = proj[e];
    }
#pragma unroll
    for (int rt = 0; rt < 2; ++rt) {
        float pv[4];
#pragma unroll
        for (int r = 0; r < 4; ++r) {
            float p = 0.0f;
#pragma unroll
            for (int n = 0; n < 16; ++n) {
                float z = acc[rt][n][r] + biasv[n];
                p += projv[n] * fast_tanh(z);
            }
            p += __shfl_xor(p, 1);
            p += __shfl_xor(p, 2);
            p += __shfl_xor(p, 4);
            p += __shfl_xor(p, 8);
            pv[r] = p;
        }
        if ((lane & 15) == 0) {
            long row = r0 + w * 32 + rt * 16 + (lane >> 4) * 4;
            float4 o; o.x = pv[0]; o.y = pv[1]; o.z = pv[2]; o.w = pv[3];
            *reinterpret_cast<float4*>(&attnS[row]) = o;   // [s][b] layout
        }
    }
}

// -------- softmax over s per batch; logits [s][b] -> attn out [b][s] --------
__global__ void r24_softmax(const float* __restrict__ attnS,
                            float* __restrict__ out_attn) {
    __shared__ float sL[SEQ];
    __shared__ float red[256];
    const int b = blockIdx.x;
    const int t = threadIdx.x;

    float lm = -1e30f;
    for (int s = t; s < SEQ; s += 256) {
        float v = attnS[(size_t)s * NB + b];
        sL[s] = v;
        lm = fmaxf(lm, v);
    }
    red[t] = lm;
    __syncthreads();
    for (int h = 128; h > 0; h >>= 1) {
        if (t < h) red[t] = fmaxf(red[t], red[t + h]);
        __syncthreads();
    }
    const float gmax = red[0];
    __syncthreads();

    float ls = 0.0f;
    for (int s = t; s < SEQ; s += 256) {
        float e = __expf(sL[s] - gmax);
        sL[s] = e;
        ls += e;
    }
    red[t] = ls;
    __syncthreads();
    for (int h = 128; h > 0; h >>= 1) {
        if (t < h) red[t] += red[t + h];
        __syncthreads();
    }
    const float inv = 1.0f / red[0];

    for (int s = t; s < SEQ; s += 256) {
        out_attn[(size_t)b * SEQ + s] = sL[s] * inv;
    }
}

// -------- float4 weighted sums over s-chunks of 256, enc [s][b][d] ----------
__global__ __launch_bounds__(256)
void r24_wsum(const float* __restrict__ enc,
              const float* __restrict__ out_attn,
              float* __restrict__ partials) {
    __shared__ float wl[256];
    __shared__ float4 pf[4][64];
    const int b  = blockIdx.x & 63;
    const int c  = blockIdx.x >> 6;      // 0..15
    const int t  = threadIdx.x;
    const int dq = t & 63;               // float4 group over d
    const int sq = t >> 6;               // s-subgroup 0..3 (64 s each)

    wl[t] = out_attn[(size_t)b * SEQ + c * 256 + t];
    __syncthreads();

    float4 acc = make_float4(0.f, 0.f, 0.f, 0.f);
    const size_t base = ((size_t)(c * 256 + sq * 64) * NB + b) * H2 + dq * 4;
#pragma unroll 4
    for (int j = 0; j < 64; ++j) {
        float wv = wl[sq * 64 + j];
        float4 ev = *reinterpret_cast<const float4*>(&enc[base + (size_t)j * NB * H2]);
        acc.x = fmaf(wv, ev.x, acc.x);
        acc.y = fmaf(wv, ev.y, acc.y);
        acc.z = fmaf(wv, ev.z, acc.z);
        acc.w = fmaf(wv, ev.w, acc.w);
    }
    pf[sq][dq] = acc;
    __syncthreads();
    if (sq == 0) {
        float4 a = pf[0][dq], b1 = pf[1][dq], c1 = pf[2][dq], d1 = pf[3][dq];
        float4 o;
        o.x = a.x + b1.x + c1.x + d1.x;
        o.y = a.y + b1.y + c1.y + d1.y;
        o.z = a.z + b1.z + c1.z + d1.z;
        o.w = a.w + b1.w + c1.w + d1.w;
        *reinterpret_cast<float4*>(&partials[((size_t)c * NB + b) * H2 + dq * 4]) = o;
    }
}

// -------- final reduce over the 16 chunks; fp32 vectors out -----------------
__global__ void r24_reduce(const float* __restrict__ partials,
                           float* __restrict__ out_vec) {
    const int b = blockIdx.x;
    const int t = threadIdx.x;           // = d
    float a = 0.0f;
#pragma unroll
    for (int c = 0; c < 16; ++c)
        a += partials[((size_t)c * NB + b) * H2 + t];
    out_vec[(size_t)b * H2 + t] = a;
}

extern "C" void kernel_launch(void* const* d_in, const int* in_sizes, int n_in,
                              void* d_out, int out_size, void* d_ws, size_t ws_size,
                              hipStream_t stream) {
    const float* enc  = (const float*)d_in[0];
    const float* W    = (const float*)d_in[1];
    const float* bias = (const float*)d_in[2];
    const float* proj = (const float*)d_in[3];

    float* out      = (float*)d_out;                 // FLOAT32 outputs
    float* out_vec  = out;                           // [1][64][256]
    float* out_attn = out + NB * H2;                 // [64][4096]

    char* ws = (char*)d_ws;
    __hip_bfloat16* Wp = (__hip_bfloat16*)ws;        // 128 KiB packed W
    float* attnS    = (float*)(ws + 131072);         // 1 MiB fp32 logits [s][b]
    float* partials = (float*)(ws + 131072 + (1u << 20));  // 1 MiB

    hipLaunchKernelGGL(pack_w_kernel,      dim3(32),          dim3(256), 0, stream,
                       W, Wp);
    hipLaunchKernelGGL(mfma_logits_kernel, dim3(MROWS / 128), dim3(256), 0, stream,
                       enc, Wp, bias, proj, attnS);
    hipLaunchKernelGGL(r24_softmax,        dim3(NB),          dim3(256), 0, stream,
                       attnS, out_attn);
    hipLaunchKernelGGL(r24_wsum,           dim3(16 * NB),     dim3(256), 0, stream,
                       enc, out_attn, partials);
    hipLaunchKernelGGL(r24_reduce,         dim3(NB),          dim3(256), 0, stream,
                       partials, out_vec);
}

// Round 25
// 128.994 us; speedup vs baseline: 1.2160x; 1.2160x over previous
//
#include <hip/hip_runtime.h>
#include <hip/hip_bf16.h>

#define SEQ 4096
#define NB 64
#define H2 256
#define MROWS (SEQ * NB)   // 262144

typedef short bf16x8 __attribute__((ext_vector_type(8)));
typedef int   i32x4  __attribute__((ext_vector_type(4)));
typedef float f32x4  __attribute__((ext_vector_type(4)));

__device__ __forceinline__ float fast_tanh(float x) {
    float e = __expf(2.0f * x);
    return 1.0f - 2.0f * __builtin_amdgcn_rcpf(e + 1.0f);
}

// -------- pack W (fp32 [256][256] d-major) -> bf16 MFMA B-fragment order ----
// Wp[((kk*16+n)*64 + l)*8 + i] = bf16(W[(kk*32 + 8*(l>>4) + i)*256 + n*16 + (l&15)])
__global__ __launch_bounds__(256)
void pack_w_kernel(const float* __restrict__ W, __hip_bfloat16* __restrict__ Wp) {
    int t = blockIdx.x * 256 + threadIdx.x;   // 0..8191
    int l  = t & 63;
    int n  = (t >> 6) & 15;
    int kk = t >> 10;
    int e  = n * 16 + (l & 15);
    int d0 = kk * 32 + 8 * (l >> 4);
    union { __hip_bfloat16 h[8]; i32x4 v; } cv;
#pragma unroll
    for (int i = 0; i < 8; ++i) cv.h[i] = __float2bfloat16(W[(d0 + i) * H2 + e]);
    *reinterpret_cast<i32x4*>(&Wp[(size_t)t * 8]) = cv.v;
}

// -------- fused MFMA logits: 128-row tile, 512 threads / 8 waves ------------
// Same tile+traffic as the R17 champion; waves/CU doubled (acc 64 VGPR/thread).
__global__ __launch_bounds__(512, 4)
void mfma_logits_kernel(const float* __restrict__ enc,
                        const __hip_bfloat16* __restrict__ Wp,
                        const float* __restrict__ bias,
                        const float* __restrict__ proj,
                        float* __restrict__ attnS) {
    __shared__ __hip_bfloat16 aT[2][128][40];   // 128 rows x 32 d (pad->40)
    __shared__ __hip_bfloat16 wT[2][8192];      // 16 KiB W-chunk per K-step

    const int tid   = threadIdx.x;              // 0..511
    const int lane  = tid & 63;
    const int w     = tid >> 6;                 // wave 0..7 -> rows w*16..+15
    const int rloc  = lane & 15;
    const int kslot = lane >> 4;
    const long r0   = (long)blockIdx.x * 128;

    f32x4 acc[16];
#pragma unroll
    for (int n = 0; n < 16; ++n) acc[n] = (f32x4)(0.0f);

    // ---- prologue: stage K-chunk 0 ----
#pragma unroll
    for (int it = 0; it < 2; ++it) {
        int q = it * 512 + tid;                 // 0..1023
        int row = q >> 3;
        int dc = (q & 7) * 4;
        float4 v = *reinterpret_cast<const float4*>(&enc[(r0 + row) * H2 + dc]);
        union { __hip_bfloat16 h[4]; uint2 u; } cv;
        cv.h[0] = __float2bfloat16(v.x); cv.h[1] = __float2bfloat16(v.y);
        cv.h[2] = __float2bfloat16(v.z); cv.h[3] = __float2bfloat16(v.w);
        *reinterpret_cast<uint2*>(&aT[0][row][dc]) = cv.u;
    }
#pragma unroll
    for (int j = 0; j < 2; ++j) {
        int idx = j * 512 + tid;                // 0..1023
        i32x4 v = *reinterpret_cast<const i32x4*>(&Wp[(size_t)idx * 8]);
        *reinterpret_cast<i32x4*>(&wT[0][idx * 8]) = v;
    }
    __syncthreads();

    int buf = 0;
#pragma unroll
    for (int kk = 0; kk < 8; ++kk) {
        // prefetch next K-chunk into registers
        float4 av[2]; i32x4 wv[2];
        if (kk < 7) {
#pragma unroll
            for (int it = 0; it < 2; ++it) {
                int q = it * 512 + tid;
                int row = q >> 3;
                int dc = (q & 7) * 4;
                av[it] = *reinterpret_cast<const float4*>(
                    &enc[(r0 + row) * H2 + (kk + 1) * 32 + dc]);
            }
#pragma unroll
            for (int j = 0; j < 2; ++j) {
                int idx = j * 512 + tid;
                wv[j] = *reinterpret_cast<const i32x4*>(
                    &Wp[(size_t)(kk + 1) * 8192 + (size_t)idx * 8]);
            }
        }
        // compute on current buffer: wave w's 16 rows x 256 cols
        bf16x8 af = *reinterpret_cast<const bf16x8*>(
            &aT[buf][w * 16 + rloc][8 * kslot]);
#pragma unroll
        for (int n = 0; n < 16; ++n) {
            bf16x8 bv = *reinterpret_cast<const bf16x8*>(&wT[buf][(n * 64 + lane) * 8]);
            acc[n] = __builtin_amdgcn_mfma_f32_16x16x32_bf16(af, bv, acc[n], 0, 0, 0);
        }
        // write prefetched data to the other buffer
        if (kk < 7) {
#pragma unroll
            for (int it = 0; it < 2; ++it) {
                int q = it * 512 + tid;
                int row = q >> 3;
                int dc = (q & 7) * 4;
                union { __hip_bfloat16 h[4]; uint2 u; } cv;
                cv.h[0] = __float2bfloat16(av[it].x); cv.h[1] = __float2bfloat16(av[it].y);
                cv.h[2] = __float2bfloat16(av[it].z); cv.h[3] = __float2bfloat16(av[it].w);
                *reinterpret_cast<uint2*>(&aT[buf ^ 1][row][dc]) = cv.u;
            }
#pragma unroll
            for (int j = 0; j < 2; ++j) {
                int idx = j * 512 + tid;
                *reinterpret_cast<i32x4*>(&wT[buf ^ 1][idx * 8]) = wv[j];
            }
        }
        __syncthreads();
        buf ^= 1;
    }

    // ---- epilogue: tanh + proj-dot + 16-lane reduce; fp32 store ----
    // D: col = n*16 + rloc, row = w*16 + kslot*4 + r
    float biasv[16], projv[16];
#pragma unroll
    for (int n = 0; n < 16; ++n) {
        int e = n * 16 + rloc;
        biasv[n] = bias[e];
        projv[n] = proj[e];
    }
    float pv[4];
#pragma unroll
    for (int r = 0; r < 4; ++r) {
        float p = 0.0f;
#pragma unroll
        for (int n = 0; n < 16; ++n)
            p += projv[n] * fast_tanh(acc[n][r] + biasv[n]);
        p += __shfl_xor(p, 1);
        p += __shfl_xor(p, 2);
        p += __shfl_xor(p, 4);
        p += __shfl_xor(p, 8);
        pv[r] = p;
    }
    if (rloc == 0) {
        long orow = r0 + w * 16 + kslot * 4;
        float4 o; o.x = pv[0]; o.y = pv[1]; o.z = pv[2]; o.w = pv[3];
        *reinterpret_cast<float4*>(&attnS[orow]) = o;   // [s][b] layout
    }
}

// -------- softmax over s per batch; logits [s][b] -> attn out [b][s] --------
__global__ void r25_softmax(const float* __restrict__ attnS,
                            float* __restrict__ out_attn) {
    __shared__ float sL[SEQ];
    __shared__ float red[256];
    const int b = blockIdx.x;
    const int t = threadIdx.x;

    float lm = -1e30f;
    for (int s = t; s < SEQ; s += 256) {
        float v = attnS[(size_t)s * NB + b];
        sL[s] = v;
        lm = fmaxf(lm, v);
    }
    red[t] = lm;
    __syncthreads();
    for (int h = 128; h > 0; h >>= 1) {
        if (t < h) red[t] = fmaxf(red[t], red[t + h]);
        __syncthreads();
    }
    const float gmax = red[0];
    __syncthreads();

    float ls = 0.0f;
    for (int s = t; s < SEQ; s += 256) {
        float e = __expf(sL[s] - gmax);
        sL[s] = e;
        ls += e;
    }
    red[t] = ls;
    __syncthreads();
    for (int h = 128; h > 0; h >>= 1) {
        if (t < h) red[t] += red[t + h];
        __syncthreads();
    }
    const float inv = 1.0f / red[0];

    for (int s = t; s < SEQ; s += 256) {
        out_attn[(size_t)b * SEQ + s] = sL[s] * inv;
    }
}

// -------- float4 weighted sums over s-chunks of 256, enc [s][b][d] ----------
__global__ __launch_bounds__(256)
void r25_wsum(const float* __restrict__ enc,
              const float* __restrict__ out_attn,
              float* __restrict__ partials) {
    __shared__ float wl[256];
    __shared__ float4 pf[4][64];
    const int b  = blockIdx.x & 63;
    const int c  = blockIdx.x >> 6;      // 0..15
    const int t  = threadIdx.x;
    const int dq = t & 63;               // float4 group over d
    const int sq = t >> 6;               // s-subgroup 0..3 (64 s each)

    wl[t] = out_attn[(size_t)b * SEQ + c * 256 + t];
    __syncthreads();

    float4 acc = make_float4(0.f, 0.f, 0.f, 0.f);
    const size_t base = ((size_t)(c * 256 + sq * 64) * NB + b) * H2 + dq * 4;
#pragma unroll 4
    for (int j = 0; j < 64; ++j) {
        float wv = wl[sq * 64 + j];
        float4 ev = *reinterpret_cast<const float4*>(&enc[base + (size_t)j * NB * H2]);
        acc.x = fmaf(wv, ev.x, acc.x);
        acc.y = fmaf(wv, ev.y, acc.y);
        acc.z = fmaf(wv, ev.z, acc.z);
        acc.w = fmaf(wv, ev.w, acc.w);
    }
    pf[sq][dq] = acc;
    __syncthreads();
    if (sq == 0) {
        float4 a = pf[0][dq], b1 = pf[1][dq], c1 = pf[2][dq], d1 = pf[3][dq];
        float4 o;
        o.x = a.x + b1.x + c1.x + d1.x;
        o.y = a.y + b1.y + c1.y + d1.y;
        o.z = a.z + b1.z + c1.z + d1.z;
        o.w = a.w + b1.w + c1.w + d1.w;
        *reinterpret_cast<float4*>(&partials[((size_t)c * NB + b) * H2 + dq * 4]) = o;
    }
}

// -------- final reduce over the 16 chunks; fp32 vectors out -----------------
__global__ void r25_reduce(const float* __restrict__ partials,
                           float* __restrict__ out_vec) {
    const int b = blockIdx.x;
    const int t = threadIdx.x;           // = d
    float a = 0.0f;
#pragma unroll
    for (int c = 0; c < 16; ++c)
        a += partials[((size_t)c * NB + b) * H2 + t];
    out_vec[(size_t)b * H2 + t] = a;
}

extern "C" void kernel_launch(void* const* d_in, const int* in_sizes, int n_in,
                              void* d_out, int out_size, void* d_ws, size_t ws_size,
                              hipStream_t stream) {
    const float* enc  = (const float*)d_in[0];
    const float* W    = (const float*)d_in[1];
    const float* bias = (const float*)d_in[2];
    const float* proj = (const float*)d_in[3];

    float* out      = (float*)d_out;                 // FLOAT32 outputs
    float* out_vec  = out;                           // [1][64][256]
    float* out_attn = out + NB * H2;                 // [64][4096]

    char* ws = (char*)d_ws;
    __hip_bfloat16* Wp = (__hip_bfloat16*)ws;        // 128 KiB packed W
    float* attnS    = (float*)(ws + 131072);         // 1 MiB fp32 logits [s][b]
    float* partials = (float*)(ws + 131072 + (1u << 20));  // 1 MiB

    hipLaunchKernelGGL(pack_w_kernel,      dim3(32),          dim3(256), 0, stream,
                       W, Wp);
    hipLaunchKernelGGL(mfma_logits_kernel, dim3(MROWS / 128), dim3(512), 0, stream,
                       enc, Wp, bias, proj, attnS);
    hipLaunchKernelGGL(r25_softmax,        dim3(NB),          dim3(256), 0, stream,
                       attnS, out_attn);
    hipLaunchKernelGGL(r25_wsum,           dim3(16 * NB),     dim3(256), 0, stream,
                       enc, out_attn, partials);
    hipLaunchKernelGGL(r25_reduce,         dim3(NB),          dim3(256), 0, stream,
                       partials, out_vec);
}